// Round 12
// baseline (40.313 us; speedup 1.0000x reference)
//
#include <hip/hip_runtime.h>
#include <hip/hip_bf16.h>

// GraspHD encoder:
//   counts[t,p,n] = sum of 8x8 block of x            (T=100, P=2, NB=300)
//   bundled[d]    = sum_{t,p,n} sin(counts*w[d]) * pos[n,d]*pol[p,d]*time[t,d]
//   out[d]        = sign(bundled[d])                 (D=4096)
// HVs are EXACTLY +-1.0f.  Sign decomposition:
//   time sign  -> xored into the sin ARGUMENT (sin(c*(+-w)) = +-sin(c*w))
//   pos sign   -> +-1.0f multiplier via v_pk_fma_f32
//   pol sign   -> applied ONCE at the epilogue (constant per d)
// sin = HW v_sin (REVOLUTIONS, range +-256; max |arg| ~46 rev), w
// pre-scaled by 1/2pi.  Trans-pipe floor = 12.5us; inner economy is
// 1 packed full-rate inst + 1 v_sin per term.
//
// R11: grid (16,250) = 4000 blocks (tail 10%->4%), n-range 6 (prologue
// halved), depth-1 REGISTER prefetch of next-k time signs AND count
// quads (SMEM latency pipelined). ws ~268 MB (measured via fill ops),
// so 250 partial rows are safe.

#define T_ 100
#define P_ 2
#define H_ 120
#define W_ 160
#define BS_ 8
#define WB_ 20
#define HB_ 15
#define NB_ 300
#define D_ 4096
#define NRN_ 50            // n-ranges, 6 n each
#define TCB_ 10            // t-pairs per block
#define GY_ 250            // partial rows = NRN_ * (50/TCB_)

typedef float f32x2 __attribute__((ext_vector_type(2)));

static __device__ __forceinline__ f32x2 splat(float v) {
    f32x2 r; r.x = v; r.y = v; return r;
}

// ---------------- kernel 1: per-block event counts (quad layout) ----------
// 480000 threads: cell = gid>>3 (60000 cells), row = gid&7.
// cell = ((t*2+p)*15 + hb)*20 + wb.  8 row-partials in consecutive lanes.
__global__ __launch_bounds__(256) void k_counts(const float* __restrict__ x,
                                                float* __restrict__ cq) {
    int gid  = blockIdx.x * 256 + threadIdx.x;
    int cell = gid >> 3;
    int row  = gid & 7;

    int wb = cell % WB_;
    int r1 = cell / WB_;
    int hb = r1 % HB_;
    int tp = r1 / HB_;

    const float4* rp = reinterpret_cast<const float4*>(
        x + ((size_t)tp * H_ + hb * BS_ + row) * W_ + wb * BS_);
    float4 a = rp[0];
    float4 b = rp[1];
    float s = (a.x + a.y + a.z + a.w) + (b.x + b.y + b.z + b.w);

    s += __shfl_xor(s, 1, 64);
    s += __shfl_xor(s, 2, 64);
    s += __shfl_xor(s, 4, 64);

    if (row == 0) {
        int t  = tp >> 1;
        int p  = tp & 1;
        int n  = hb * WB_ + wb;
        int tc = t >> 1;
        int tl = t & 1;
        cq[(((size_t)tc * NB_ + n) << 2) + tl * 2 + p] = s;
    }
}

// ---------------- kernel 2: main bind+bundle partial sums ----------------
// grid (16, 250).  y -> (tcg, nr): tc in [tcg*10,+10), n in [nr*6,+6).
// Each thread owns one d.  Inner: j-pairs -> 8 independent sin chains.
// Depth-1 register pipeline on next-k time signs and count quads.
__global__ __launch_bounds__(256) void k_encode(const float4* __restrict__ cq,
                                                const float* __restrict__ proj_w,
                                                const float* __restrict__ pos_hv,
                                                const float* __restrict__ pol_hv,
                                                const float* __restrict__ time_hv,
                                                float* __restrict__ partial) {
    const int d   = blockIdx.x * 256 + threadIdx.x;
    const int y   = blockIdx.y;
    const int tcg = y / NRN_;
    const int nr  = y - tcg * NRN_;
    const int n0  = nr * 6;
    const int tc0 = tcg * TCB_;
    const int t0  = tc0 * 2;

    const unsigned SGN = 0x80000000u;
    const unsigned uw  = __float_as_uint(proj_w[d] * 0.15915494309189535f);

    // hoist raw pos values (+-1.0f); pol deferred to epilogue
    float pf[6];
#pragma unroll
    for (int j = 0; j < 6; ++j)
        pf[j] = pos_hv[(size_t)(n0 + j) * D_ + d];

    f32x2 accA = {0.f, 0.f};   // t-even {p0, p1} partial (pol not applied)
    f32x2 accB = {0.f, 0.f};   // t-odd  {p0, p1}

    const float4* cb = cq + (size_t)tc0 * NB_ + n0;       // wave-uniform
    const float*  th = time_hv + (size_t)t0 * D_ + d;

    // depth-1 pipeline: time signs + count quads for iteration k
    unsigned sa = __float_as_uint(th[0])          & SGN;
    unsigned sb = __float_as_uint(th[(size_t)D_]) & SGN;
    float4 q0 = cb[0], q1 = cb[1], q2 = cb[2];
    float4 q3 = cb[3], q4 = cb[4], q5 = cb[5];

#pragma unroll
    for (int k = 0; k < TCB_; ++k) {
        // prefetch k+1 (wave-uniform s_loads, land while k computes)
        unsigned nsa = 0u, nsb = 0u;
        float4 p0, p1, p2, p3, p4, p5;
        if (k + 1 < TCB_) {
            nsa = __float_as_uint(th[(size_t)(2 * k + 2) * D_]) & SGN;
            nsb = __float_as_uint(th[(size_t)(2 * k + 3) * D_]) & SGN;
            const float4* cn = cb + (size_t)(k + 1) * NB_;
            p0 = cn[0]; p1 = cn[1]; p2 = cn[2];
            p3 = cn[3]; p4 = cn[4]; p5 = cn[5];
        }

        const f32x2 wA = splat(__uint_as_float(uw ^ sa));   // t-even +-w
        const f32x2 wB = splat(__uint_as_float(uw ^ sb));   // t-odd  +-w

        const float4 qq[6] = {q0, q1, q2, q3, q4, q5};
#pragma unroll
        for (int j = 0; j < 6; j += 2) {
            float4 cj0 = qq[j];
            float4 cj1 = qq[j + 1];
            f32x2 a01; a01.x = cj0.x; a01.y = cj0.y;      // n=j,   t-even {p0,p1}
            f32x2 a23; a23.x = cj0.z; a23.y = cj0.w;      // n=j,   t-odd
            f32x2 b01; b01.x = cj1.x; b01.y = cj1.y;      // n=j+1, t-even
            f32x2 b23; b23.x = cj1.z; b23.y = cj1.w;      // n=j+1, t-odd

            f32x2 pa0 = a01 * wA;                         // v_pk_mul_f32 x4
            f32x2 pa1 = a23 * wB;
            f32x2 pb0 = b01 * wA;
            f32x2 pb1 = b23 * wB;

            f32x2 s1, s2, s3, s4;                         // 8 independent sins
            s1.x = __builtin_amdgcn_sinf(pa0.x);
            s1.y = __builtin_amdgcn_sinf(pa0.y);
            s2.x = __builtin_amdgcn_sinf(pa1.x);
            s2.y = __builtin_amdgcn_sinf(pa1.y);
            s3.x = __builtin_amdgcn_sinf(pb0.x);
            s3.y = __builtin_amdgcn_sinf(pb0.y);
            s4.x = __builtin_amdgcn_sinf(pb1.x);
            s4.y = __builtin_amdgcn_sinf(pb1.y);

            const f32x2 g0 = splat(pf[j]);                // pos sign as +-1.0
            const f32x2 g1 = splat(pf[j + 1]);
            accA += s1 * g0;                              // v_pk_fma_f32 x4
            accB += s2 * g0;
            accA += s3 * g1;
            accB += s4 * g1;
        }
        sa = nsa; sb = nsb;
        q0 = p0; q1 = p1; q2 = p2; q3 = p3; q4 = p4; q5 = p5;
    }

    // epilogue: apply polarity (+-1.0f), combine t-even/t-odd
    const float pol0 = pol_hv[d];
    const float pol1 = pol_hv[D_ + d];
    partial[(size_t)y * D_ + d] =
        (accA.x + accB.x) * pol0 + (accA.y + accB.y) * pol1;
}

// ---------------- kernel 3: single-launch reduce + sign ------------------
// grid 64 blocks, block (64,10) = 10 waves. Wave w sums 25 rows for its
// 64 d's; LDS combine; wave 0 writes sign. Deterministic order.
__global__ __launch_bounds__(640) void k_reduce(const float* __restrict__ partial,
                                                float* __restrict__ out) {
    __shared__ float red[10][64];
    const int lane = threadIdx.x;          // 0..63
    const int w    = threadIdx.y;          // 0..9
    const int d    = blockIdx.x * 64 + lane;
    float a = 0.f;
#pragma unroll
    for (int i = 0; i < GY_ / 10; ++i)
        a += partial[(size_t)(w * (GY_ / 10) + i) * D_ + d];
    red[w][lane] = a;
    __syncthreads();
    if (w == 0) {
        float s = (((red[0][lane] + red[1][lane]) + (red[2][lane] + red[3][lane]))
                +  ((red[4][lane] + red[5][lane]) + (red[6][lane] + red[7][lane])))
                +   (red[8][lane] + red[9][lane]);
        out[d] = (s > 0.f) ? 1.f : ((s < 0.f) ? -1.f : 0.f);
    }
}

extern "C" void kernel_launch(void* const* d_in, const int* in_sizes, int n_in,
                              void* d_out, int out_size, void* d_ws, size_t ws_size,
                              hipStream_t stream) {
    const float* x       = (const float*)d_in[0];
    const float* proj_w  = (const float*)d_in[1];
    const float* pos_hv  = (const float*)d_in[2];
    const float* pol_hv  = (const float*)d_in[3];
    const float* time_hv = (const float*)d_in[4];
    float* out = (float*)d_out;

    // ws layout: counts_q (15000 float4, 240 KB) at 0; partial (250*D f32,
    // 4 MB) at 256 KiB.  ws_size ~268 MB (measured from harness poison).
    float* counts_q = (float*)d_ws;
    float* partial  = (float*)((char*)d_ws + (256u << 10));

    // 480000 threads = 1875 blocks: one thread per (quad-cell, row)
    k_counts<<<dim3(1875), dim3(256), 0, stream>>>(x, counts_q);

    k_encode<<<dim3(16, GY_), dim3(256), 0, stream>>>(
        (const float4*)counts_q, proj_w, pos_hv, pol_hv, time_hv, partial);
    k_reduce<<<dim3(D_ / 64), dim3(64, 10), 0, stream>>>(partial, out);
}

// Round 13
// 37.092 us; speedup vs baseline: 1.0868x; 1.0868x over previous
//
#include <hip/hip_runtime.h>
#include <hip/hip_bf16.h>

// GraspHD encoder:
//   counts[t,p,n] = sum of 8x8 block of x            (T=100, P=2, NB=300)
//   bundled[d]    = sum_{t,p,n} sin(counts*w[d]) * pos[n,d]*pol[p,d]*time[t,d]
//   out[d]        = sign(bundled[d])                 (D=4096)
// HVs are EXACTLY +-1.0f.  Sign decomposition:
//   time sign  -> xored into the sin ARGUMENT (sin(c*(+-w)) = +-sin(c*w))
//   pos sign   -> +-1.0f multiplier via v_pk_fma_f32
//   pol sign   -> applied ONCE at the epilogue (constant per d)
// sin = HW v_sin (REVOLUTIONS, range +-256; max |arg| ~46 rev), w
// pre-scaled by 1/2pi.  Inner economy: 16 insts per 8 terms
// (4 pk_mul + 8 v_sin + 4 pk_fma).
//
// R12: R10 core (best: 37.96us) with 64-thread encode blocks:
// grid (64,125) = 8000 single-wave blocks = 31.25 waves/CU -> the
// end-of-kernel imbalance tail drops from ~12% (7.81 blocks/CU at
// 256-thread blocks) to ~3%.  Inner loop untouched.

#define T_ 100
#define P_ 2
#define H_ 120
#define W_ 160
#define BS_ 8
#define WB_ 20
#define HB_ 15
#define NB_ 300
#define D_ 4096
#define NR_ 25             // n-ranges, 12 n each
#define TCB_ 10            // t-pairs per block
#define GY_ 125            // partial rows

typedef float f32x2 __attribute__((ext_vector_type(2)));

static __device__ __forceinline__ f32x2 splat(float v) {
    f32x2 r; r.x = v; r.y = v; return r;
}

// ---------------- kernel 1: per-block event counts (quad layout) ----------
// 480000 threads: cell = gid>>3 (60000 cells), row = gid&7.
// cell = ((t*2+p)*15 + hb)*20 + wb.  8 row-partials in consecutive lanes.
__global__ __launch_bounds__(256) void k_counts(const float* __restrict__ x,
                                                float* __restrict__ cq) {
    int gid  = blockIdx.x * 256 + threadIdx.x;
    int cell = gid >> 3;
    int row  = gid & 7;

    int wb = cell % WB_;
    int r1 = cell / WB_;
    int hb = r1 % HB_;
    int tp = r1 / HB_;

    const float4* rp = reinterpret_cast<const float4*>(
        x + ((size_t)tp * H_ + hb * BS_ + row) * W_ + wb * BS_);
    float4 a = rp[0];
    float4 b = rp[1];
    float s = (a.x + a.y + a.z + a.w) + (b.x + b.y + b.z + b.w);

    s += __shfl_xor(s, 1, 64);
    s += __shfl_xor(s, 2, 64);
    s += __shfl_xor(s, 4, 64);

    if (row == 0) {
        int t  = tp >> 1;
        int p  = tp & 1;
        int n  = hb * WB_ + wb;
        int tc = t >> 1;
        int tl = t & 1;
        cq[(((size_t)tc * NB_ + n) << 2) + tl * 2 + p] = s;
    }
}

// ---------------- kernel 2: main bind+bundle partial sums ----------------
// grid (64, 125), block 64 (one wave).  y -> (tcg, nr): tc in [tcg*10,+10),
// n in [nr*12,+12).  Each thread owns one d.  Inner loop: j-pairs -> 8
// independent mul->sin->fma chains; pol applied at epilogue.
__global__ __launch_bounds__(64) void k_encode(const float4* __restrict__ cq,
                                               const float* __restrict__ proj_w,
                                               const float* __restrict__ pos_hv,
                                               const float* __restrict__ pol_hv,
                                               const float* __restrict__ time_hv,
                                               float* __restrict__ partial) {
    const int d   = blockIdx.x * 64 + threadIdx.x;
    const int y   = blockIdx.y;
    const int tcg = y / NR_;
    const int nr  = y - tcg * NR_;
    const int n0  = nr * 12;
    const int tc0 = tcg * TCB_;
    const int t0  = tc0 * 2;

    const unsigned SGN = 0x80000000u;
    const unsigned uw  = __float_as_uint(proj_w[d] * 0.15915494309189535f);

    // hoist raw pos values (+-1.0f); pol deferred to epilogue
    float pf[12];
#pragma unroll
    for (int j = 0; j < 12; ++j)
        pf[j] = pos_hv[(size_t)(n0 + j) * D_ + d];

    f32x2 accA = {0.f, 0.f};   // t-even {p0, p1} partial (pol not applied)
    f32x2 accB = {0.f, 0.f};   // t-odd  {p0, p1}

    const float4* cb = cq + (size_t)tc0 * NB_ + n0;       // wave-uniform
    const float*  th = time_hv + (size_t)t0 * D_ + d;

    // depth-1 software pipeline on the per-k time-sign loads
    unsigned sa = __float_as_uint(th[0])          & SGN;
    unsigned sb = __float_as_uint(th[(size_t)D_]) & SGN;

#pragma unroll 2
    for (int k = 0; k < TCB_; ++k) {
        unsigned nsa = 0u, nsb = 0u;
        if (k + 1 < TCB_) {
            nsa = __float_as_uint(th[(size_t)(2 * k + 2) * D_]) & SGN;
            nsb = __float_as_uint(th[(size_t)(2 * k + 3) * D_]) & SGN;
        }
        const f32x2 wA = splat(__uint_as_float(uw ^ sa));   // t-even +-w
        const f32x2 wB = splat(__uint_as_float(uw ^ sb));   // t-odd  +-w
        const float4* ck = cb + (size_t)k * NB_;
#pragma unroll
        for (int j = 0; j < 12; j += 2) {
            float4 cj0 = ck[j];                           // contiguous s_loads
            float4 cj1 = ck[j + 1];
            f32x2 a01; a01.x = cj0.x; a01.y = cj0.y;      // n=j,   t-even {p0,p1}
            f32x2 a23; a23.x = cj0.z; a23.y = cj0.w;      // n=j,   t-odd
            f32x2 b01; b01.x = cj1.x; b01.y = cj1.y;      // n=j+1, t-even
            f32x2 b23; b23.x = cj1.z; b23.y = cj1.w;      // n=j+1, t-odd

            f32x2 pa0 = a01 * wA;                         // v_pk_mul_f32 x4
            f32x2 pa1 = a23 * wB;
            f32x2 pb0 = b01 * wA;
            f32x2 pb1 = b23 * wB;

            f32x2 s1, s2, s3, s4;                         // 8 independent sins
            s1.x = __builtin_amdgcn_sinf(pa0.x);
            s1.y = __builtin_amdgcn_sinf(pa0.y);
            s2.x = __builtin_amdgcn_sinf(pa1.x);
            s2.y = __builtin_amdgcn_sinf(pa1.y);
            s3.x = __builtin_amdgcn_sinf(pb0.x);
            s3.y = __builtin_amdgcn_sinf(pb0.y);
            s4.x = __builtin_amdgcn_sinf(pb1.x);
            s4.y = __builtin_amdgcn_sinf(pb1.y);

            const f32x2 g0 = splat(pf[j]);                // pos sign as +-1.0
            const f32x2 g1 = splat(pf[j + 1]);
            accA += s1 * g0;                              // v_pk_fma_f32 x4
            accB += s2 * g0;
            accA += s3 * g1;
            accB += s4 * g1;
        }
        sa = nsa;
        sb = nsb;
    }

    // epilogue: apply polarity (+-1.0f), combine t-even/t-odd
    const float pol0 = pol_hv[d];
    const float pol1 = pol_hv[D_ + d];
    partial[(size_t)y * D_ + d] =
        (accA.x + accB.x) * pol0 + (accA.y + accB.y) * pol1;
}

// ---------------- kernel 3: single-launch reduce + sign ------------------
// grid 64 blocks, block (64,5) = 5 waves. Wave w sums 25 rows for its
// 64 d's; LDS combine; wave 0 writes sign. Deterministic order.
__global__ __launch_bounds__(320) void k_reduce(const float* __restrict__ partial,
                                                float* __restrict__ out) {
    __shared__ float red[5][64];
    const int lane = threadIdx.x;          // 0..63
    const int w    = threadIdx.y;          // 0..4
    const int d    = blockIdx.x * 64 + lane;
    float a = 0.f;
#pragma unroll
    for (int i = 0; i < GY_ / 5; ++i)
        a += partial[(size_t)(w * (GY_ / 5) + i) * D_ + d];
    red[w][lane] = a;
    __syncthreads();
    if (w == 0) {
        float s = ((red[0][lane] + red[1][lane]) + (red[2][lane] + red[3][lane]))
                  + red[4][lane];
        out[d] = (s > 0.f) ? 1.f : ((s < 0.f) ? -1.f : 0.f);
    }
}

extern "C" void kernel_launch(void* const* d_in, const int* in_sizes, int n_in,
                              void* d_out, int out_size, void* d_ws, size_t ws_size,
                              hipStream_t stream) {
    const float* x       = (const float*)d_in[0];
    const float* proj_w  = (const float*)d_in[1];
    const float* pos_hv  = (const float*)d_in[2];
    const float* pol_hv  = (const float*)d_in[3];
    const float* time_hv = (const float*)d_in[4];
    float* out = (float*)d_out;

    // ws layout: counts_q (15000 float4, 240 KB) at 0; partial (125*D f32,
    // 2 MB) at 256 KiB.  ws_size ~268 MB (measured) — ample.
    float* counts_q = (float*)d_ws;
    float* partial  = (float*)((char*)d_ws + (256u << 10));

    // 480000 threads = 1875 blocks: one thread per (quad-cell, row)
    k_counts<<<dim3(1875), dim3(256), 0, stream>>>(x, counts_q);

    k_encode<<<dim3(64, GY_), dim3(64), 0, stream>>>(
        (const float4*)counts_q, proj_w, pos_hv, pol_hv, time_hv, partial);
    k_reduce<<<dim3(D_ / 64), dim3(64, 5), 0, stream>>>(partial, out);
}